// Round 2
// baseline (831.430 us; speedup 1.0000x reference)
//
#include <hip/hip_runtime.h>

#define VOCAB 400000
#define DIM   300
#define HID   32
#define NOUT  2
#define BATCH 16384
#define SEQ   50

// K1: one wave (64 lanes) per batch row.
// - All 50 tokens prefetched with ONE coalesced load (lanes 0..49), then
//   broadcast via __shfl -> gather addresses have no memory dependency.
// - Gathers issued in independent groups of 5 (10 load instrs in flight).
// - pooled kept in registers (lane l owns float4 l, lanes 0..10 also 64+l).
// - h = relu(pooled @ Vw^T + Vb) via per-lane partial dots (Vw phased in two
//   16-row halves so each 19.2KB phase stays L1-resident) + shfl_xor butterfly.
__global__ __launch_bounds__(256) void dan_main(
    const int*   __restrict__ tokens,
    const float* __restrict__ emb,
    const float* __restrict__ Vw,
    const float* __restrict__ Vb,
    const float* __restrict__ Ww,
    const float* __restrict__ Wb,
    float*       __restrict__ logits)
{
    const int wave = threadIdx.x >> 6;
    const int lane = threadIdx.x & 63;
    const int row  = blockIdx.x * 4 + wave;
    if (row >= BATCH) return;

    // One coalesced token load per wave; no per-iteration token loads.
    int tl = 0;
    if (lane < SEQ) tl = tokens[row * SEQ + lane];

    const bool has1 = (lane < (DIM / 4 - 64));  // lanes 0..10 own float4 64+l

    float4 a0 = make_float4(0.f, 0.f, 0.f, 0.f);
    float4 a1 = make_float4(0.f, 0.f, 0.f, 0.f);

    // 50 = 10 groups of 5 independent gathers.
    for (int s0 = 0; s0 < SEQ; s0 += 5) {
        const float4* e[5];
        #pragma unroll
        for (int j = 0; j < 5; ++j) {
            const int t = __shfl(tl, s0 + j, 64);
            e[j] = (const float4*)(emb + (size_t)t * DIM);
        }
        float4 v0[5];
        #pragma unroll
        for (int j = 0; j < 5; ++j) v0[j] = e[j][lane];
        float4 v1[5];
        if (has1) {
            #pragma unroll
            for (int j = 0; j < 5; ++j) v1[j] = e[j][64 + lane];
        }
        #pragma unroll
        for (int j = 0; j < 5; ++j) {
            a0.x += v0[j].x; a0.y += v0[j].y; a0.z += v0[j].z; a0.w += v0[j].w;
        }
        if (has1) {
            #pragma unroll
            for (int j = 0; j < 5; ++j) {
                a1.x += v1[j].x; a1.y += v1[j].y; a1.z += v1[j].z; a1.w += v1[j].w;
            }
        }
    }
    const float inv = 1.0f / (float)SEQ;
    a0.x *= inv; a0.y *= inv; a0.z *= inv; a0.w *= inv;
    a1.x *= inv; a1.y *= inv; a1.z *= inv; a1.w *= inv;

    // Per-lane partial dots for 32 hidden units, phased 2x16 for L1 residency.
    float hp[HID];
    #pragma unroll
    for (int half = 0; half < 2; ++half) {
        #pragma unroll
        for (int kk = 0; kk < 16; ++kk) {
            const int k = half * 16 + kk;
            const float4* vr = (const float4*)(Vw + k * DIM);
            float4 w0 = vr[lane];
            float p = a0.x * w0.x + a0.y * w0.y + a0.z * w0.z + a0.w * w0.w;
            if (has1) {
                float4 w1 = vr[64 + lane];
                p += a1.x * w1.x + a1.y * w1.y + a1.z * w1.z + a1.w * w1.w;
            }
            hp[k] = p;
        }
    }

    // Butterfly reduce across 64 lanes; every lane ends with full sums.
    #pragma unroll
    for (int m = 1; m < 64; m <<= 1) {
        #pragma unroll
        for (int k = 0; k < HID; ++k)
            hp[k] += __shfl_xor(hp[k], m, 64);
    }

    float l0 = Wb[0], l1 = Wb[1];
    #pragma unroll
    for (int k = 0; k < HID; ++k) {
        float h = hp[k] + Vb[k];
        h = h > 0.f ? h : 0.f;
        l0 += h * Ww[k];
        l1 += h * Ww[HID + k];
    }
    if (lane == 0) {
        ((float2*)logits)[row] = make_float2(l0, l1);
    }
}

// K2: single block computes per-column (axis=0) max and log-sum-exp.
__global__ __launch_bounds__(1024) void dan_reduce(
    const float* __restrict__ logits, float* __restrict__ c)
{
    __shared__ float r0[1024];
    __shared__ float r1[1024];
    const int tid = threadIdx.x;
    const float2* lp = (const float2*)logits;

    float m0 = -INFINITY, m1 = -INFINITY;
    for (int b = tid; b < BATCH; b += 1024) {
        float2 v = lp[b];
        m0 = fmaxf(m0, v.x);
        m1 = fmaxf(m1, v.y);
    }
    r0[tid] = m0; r1[tid] = m1;
    __syncthreads();
    for (int s = 512; s > 0; s >>= 1) {
        if (tid < s) {
            r0[tid] = fmaxf(r0[tid], r0[tid + s]);
            r1[tid] = fmaxf(r1[tid], r1[tid + s]);
        }
        __syncthreads();
    }
    m0 = r0[0]; m1 = r1[0];
    __syncthreads();

    float s0 = 0.f, s1 = 0.f;
    for (int b = tid; b < BATCH; b += 1024) {
        float2 v = lp[b];
        s0 += __expf(v.x - m0);
        s1 += __expf(v.y - m1);
    }
    r0[tid] = s0; r1[tid] = s1;
    __syncthreads();
    for (int s = 512; s > 0; s >>= 1) {
        if (tid < s) {
            r0[tid] += r0[tid + s];
            r1[tid] += r1[tid + s];
        }
        __syncthreads();
    }
    if (tid == 0) {
        c[0] = m0 + __logf(r0[0]);
        c[1] = m1 + __logf(r1[0]);
    }
}

// K3: out[b][j] = logits[b][j] - c[j], float2-vectorized.
__global__ __launch_bounds__(256) void dan_final(
    const float* __restrict__ logits, const float* __restrict__ c,
    float* __restrict__ out)
{
    const int b = blockIdx.x * blockDim.x + threadIdx.x;
    if (b < BATCH) {
        float2 v = ((const float2*)logits)[b];
        ((float2*)out)[b] = make_float2(v.x - c[0], v.y - c[1]);
    }
}

extern "C" void kernel_launch(void* const* d_in, const int* in_sizes, int n_in,
                              void* d_out, int out_size, void* d_ws, size_t ws_size,
                              hipStream_t stream) {
    const int*   tokens = (const int*)  d_in[0];
    const float* emb    = (const float*)d_in[1];
    const float* Vw     = (const float*)d_in[2];
    const float* Vb     = (const float*)d_in[3];
    const float* Ww     = (const float*)d_in[4];
    const float* Wb     = (const float*)d_in[5];
    float* out    = (float*)d_out;
    float* logits = (float*)d_ws;                 // BATCH*NOUT floats = 128 KB
    float* c      = logits + BATCH * NOUT;        // 2 floats

    dan_main  <<<BATCH / 4, 256, 0, stream>>>(tokens, emb, Vw, Vb, Ww, Wb, logits);
    dan_reduce<<<1, 1024, 0, stream>>>(logits, c);
    dan_final <<<(BATCH + 255) / 256, 256, 0, stream>>>(logits, c, out);
}